// Round 10
// baseline (262.137 us; speedup 1.0000x reference)
//
#include <hip/hip_runtime.h>
#include <hip/hip_bf16.h>

#define BB 4
#define CC 64
#define HH 128
#define WW 128
#define HW (HH * WW)
#define OCP 20  // offset channels, padded (18 used)

typedef short bf16x8 __attribute__((ext_vector_type(8)));
typedef float f32x4 __attribute__((ext_vector_type(4)));
typedef float f32x2 __attribute__((ext_vector_type(2)));

static __device__ __forceinline__ short f2bf(float f) {
  __hip_bfloat16 h = __float2bfloat16(f);
  return __builtin_bit_cast(short, h);
}
static __device__ __forceinline__ float bf2f(short s) {
  unsigned int u = ((unsigned int)(unsigned short)s) << 16;
  return __builtin_bit_cast(float, u);
}

// async 16B/lane global -> LDS (wave-uniform LDS base + lane*16)
static __device__ __forceinline__ void stage1k(const short* g, short* lds) {
  __builtin_amdgcn_global_load_lds(
      (const __attribute__((address_space(1))) unsigned int*)g,
      (__attribute__((address_space(3))) unsigned int*)lds, 16, 0, 0);
}

// NCHW f32 -> NHWC bf16 for two tensors. Block = 64 px x 64 c tile.
__global__ __launch_bounds__(256) void cast_nhwc_kernel(
    const float* __restrict__ a, const float* __restrict__ b,
    short* __restrict__ oa, short* __restrict__ ob) {
  __shared__ float tile[64][68];
  const int bid = blockIdx.x;        // 1024 blocks
  const int bb = bid >> 8;           // batch
  const int hw0 = (bid & 255) * 64;  // 64-px stripe
  const int t = threadIdx.x;
  for (int s = 0; s < 2; s++) {
    const float* src = s ? b : a;
    short* dst = s ? ob : oa;
    if (s) __syncthreads();
    {
      const int lp = t & 15;  // 16 lanes x float4 = 64 px
      for (int c = (t >> 4); c < 64; c += 16) {
        float4 v = *(const float4*)&src[((size_t)(bb * 64 + c)) * HW + hw0 + lp * 4];
        *(float4*)&tile[c][lp * 4] = v;
      }
    }
    __syncthreads();
    {
      const int px = t >> 2;
      const int seg = t & 3;
      bf16x8 s0, s1;
#pragma unroll
      for (int i = 0; i < 8; i++) s0[i] = f2bf(tile[seg * 16 + i][px]);
#pragma unroll
      for (int i = 0; i < 8; i++) s1[i] = f2bf(tile[seg * 16 + 8 + i][px]);
      short* dp = dst + ((size_t)(bid * 64 + px)) * 64 + seg * 16;
      *(bf16x8*)dp = s0;
      *(bf16x8*)(dp + 8) = s1;
    }
  }
}

// Weight prep, all 3 stages in one launch (stage = blockIdx.x/144).
// deform wd (64,64,3,3) -> A-frags [f = k*8+cf*4+ot][lane][8]:
//   o = ot*16+(l&15), c = cf*32+(l>>4)*8+j
// offset wo (18,128,3,3) -> A-frags [f = (k*4+cs)*2+ot][lane][8]:
//   o = ot*16+(l&15) (zero if o>=18), c = cs*32+(l>>4)*8+j
__global__ __launch_bounds__(256) void prep_weights_all(
    const float* __restrict__ wd1, const float* __restrict__ wo1,
    short* __restrict__ wtd1, short* __restrict__ wtoff1,
    const float* __restrict__ wd2, const float* __restrict__ wo2,
    short* __restrict__ wtd2, short* __restrict__ wtoff2,
    const float* __restrict__ wd3, const float* __restrict__ wo3,
    short* __restrict__ wtd3, short* __restrict__ wtoff3) {
  const int s = blockIdx.x / 144;
  const float* wd = (s == 0) ? wd1 : (s == 1) ? wd2 : wd3;
  const float* wo = (s == 0) ? wo1 : (s == 1) ? wo2 : wo3;
  short* wtd = (s == 0) ? wtd1 : (s == 1) ? wtd2 : wtd3;
  short* wtoff = (s == 0) ? wtoff1 : (s == 1) ? wtoff2 : wtoff3;
  const int i = (blockIdx.x % 144) * 256 + threadIdx.x;  // 0..36863
  const int j = i & 7, l = (i >> 3) & 63, f = i >> 9;
  {
    int ot = f & 3, cf = (f >> 2) & 1, k = f >> 3;
    int o = ot * 16 + (l & 15), c = cf * 32 + (l >> 4) * 8 + j;
    wtd[i] = f2bf(wd[(o * 64 + c) * 9 + k]);
  }
  {
    int ot = f & 1, ks = f >> 1;
    int cs = ks & 3, k = ks >> 2;
    int o = ot * 16 + (l & 15), c = cs * 32 + (l >> 4) * 8 + j;
    wtoff[i] = (o < 18) ? f2bf(wo[(o * 128 + c) * 9 + k]) : (short)0;
  }
}

// ---------- MFMA offset conv, split-K(cs) across 4 waves ----------
// Block = 256 thr = 4 waves, ONE 16-px group. Wave cs handles 32 input
// channels (cs<2: ref, else x2). LDS tree-reduce partial accumulators.
__global__ __launch_bounds__(256, 8) void off_conv_kernel(
    const short* __restrict__ ref, const short* __restrict__ x2,
    const short* __restrict__ wtoff, const float* __restrict__ bias,
    float* __restrict__ out) {
  __shared__ float red[2][64][9];
  int bid = blockIdx.x;
  bid = (bid & 7) * (gridDim.x >> 3) + (bid >> 3);  // XCD swizzle (4096%8==0)
  const int tid = threadIdx.x;
  const int l = tid & 63;
  const int cs = __builtin_amdgcn_readfirstlane(tid >> 6);  // wave = c-slice
  const int col = l & 15, quad = l >> 4;
  const int pix = bid * 16 + col;
  const int b = pix >> 14, hw = pix & (HW - 1);
  const int h = hw >> 7, w = hw & (WW - 1);

  f32x4 acc0 = {0.f, 0.f, 0.f, 0.f}, acc1 = {0.f, 0.f, 0.f, 0.f};
  const int c0 = (cs & 1) * 32 + quad * 8;
  const short* src = (cs < 2) ? ref : x2;
  const bf16x8* wp = (const bf16x8*)wtoff + l;

#pragma unroll
  for (int k = 0; k < 9; k++) {
    const int ky = k / 3, kx = k - ky * 3;
    const int hh = h + ky - 1, ww2 = w + kx - 1;
    const bool valid = (hh >= 0) & (hh < HH) & (ww2 >= 0) & (ww2 < WW);
    const int chh = min(max(hh, 0), HH - 1), cww = min(max(ww2, 0), WW - 1);
    bf16x8 v = *(const bf16x8*)(src + ((b * HW + chh * WW + cww) << 6) + c0);
    if (!valid) v = (bf16x8)(short)0;
    acc0 = __builtin_amdgcn_mfma_f32_16x16x32_bf16(
        wp[((k * 4 + cs) * 2 + 0) * 64], v, acc0, 0, 0, 0);
    acc1 = __builtin_amdgcn_mfma_f32_16x16x32_bf16(
        wp[((k * 4 + cs) * 2 + 1) * 64], v, acc1, 0, 0, 0);
  }

  // tree reduce: 4 -> 2 -> 1
  if (cs >= 2) {
#pragma unroll
    for (int r = 0; r < 4; r++) {
      red[cs - 2][l][r] = acc0[r];
      red[cs - 2][l][4 + r] = acc1[r];
    }
  }
  __syncthreads();
  if (cs < 2) {
#pragma unroll
    for (int r = 0; r < 4; r++) {
      acc0[r] += red[cs][l][r];
      acc1[r] += red[cs][l][4 + r];
    }
  }
  __syncthreads();
  if (cs == 1) {
#pragma unroll
    for (int r = 0; r < 4; r++) {
      red[0][l][r] = acc0[r];
      red[0][l][4 + r] = acc1[r];
    }
  }
  __syncthreads();
  if (cs == 0) {
    float* po = out + (size_t)pix * OCP;
#pragma unroll
    for (int r = 0; r < 4; r++)
      po[quad * 4 + r] = acc0[r] + red[0][l][r] + bias[quad * 4 + r];
    if (quad == 0) {
      po[16] = acc1[0] + red[0][l][4] + bias[16];
      po[17] = acc1[1] + red[0][l][5] + bias[17];
    }
  }
}

// ---------- MFMA deformable conv, channel-half split-K ----------
// Block = 512 thr = 4 px-groups x 2 cf-waves. Weights double-buffer-staged
// into LDS per tap via global_load_lds (1 async 1KB load per wave); weight
// frags then come from conflict-free ds_read_b128. Act gathers own the
// VMEM path (36/wave instead of 72).
__global__ __launch_bounds__(512, 8) void deform_cf_kernel(
    const short* __restrict__ x, const float* __restrict__ off,
    const short* __restrict__ wtd, const float* __restrict__ bias,
    float* __restrict__ outf, short* __restrict__ outb) {
  __shared__ short wlds[2][4096];   // 2 x 8KB: one tap's 8 A-frags
  __shared__ float red[4][64][17];
  int bid = blockIdx.x;
  bid = (bid & 7) * (gridDim.x >> 3) + (bid >> 3);  // 1024 % 8 == 0
  const int tid = threadIdx.x;
  const int l = tid & 63;
  const int wv = __builtin_amdgcn_readfirstlane(tid >> 6);  // 0..7
  const int grp = wv >> 1;  // px group 0..3
  const int cf = wv & 1;    // channel half
  const int col = l & 15, quad = l >> 4;
  const int pix = bid * 64 + grp * 16 + col;
  const int b = pix >> 14, hw = pix & (HW - 1);
  const int h = hw >> 7, w = hw & (WW - 1);

  const short* xb = x + (size_t)b * (HW * 64);
  const float* offp = off + (size_t)pix * OCP;

  // all 18 offset values in 5 vector loads
  f32x4 ov0 = *(const f32x4*)(offp);
  f32x4 ov1 = *(const f32x4*)(offp + 4);
  f32x4 ov2 = *(const f32x4*)(offp + 8);
  f32x4 ov3 = *(const f32x4*)(offp + 12);
  f32x2 ov4 = *(const f32x2*)(offp + 16);
  float offv[18];
#pragma unroll
  for (int i = 0; i < 4; i++) offv[i] = ov0[i];
#pragma unroll
  for (int i = 0; i < 4; i++) offv[4 + i] = ov1[i];
#pragma unroll
  for (int i = 0; i < 4; i++) offv[8 + i] = ov2[i];
#pragma unroll
  for (int i = 0; i < 4; i++) offv[12 + i] = ov3[i];
  offv[16] = ov4[0];
  offv[17] = ov4[1];

  f32x4 acc[4];
#pragma unroll
  for (int ot = 0; ot < 4; ot++)
#pragma unroll
    for (int r = 0; r < 4; r++) acc[ot][r] = 0.f;

  const int c0 = cf * 32 + quad * 8;

  // stage tap 0: wave wv copies frag (0*8 + wv) -> wlds[0][wv*512..]
  stage1k(wtd + (0 * 8 + wv) * 512 + l * 8, &wlds[0][wv * 512]);
  __syncthreads();

#pragma unroll
  for (int k = 0; k < 9; k++) {
    const int buf = k & 1;
    if (k < 8)  // async-stage next tap into alternate buffer
      stage1k(wtd + ((k + 1) * 8 + wv) * 512 + l * 8, &wlds[buf ^ 1][wv * 512]);

    const int ky = k / 3, kx = k - ky * 3;
    const float py = (float)(h - 1 + ky) + offv[2 * k];
    const float pxx = (float)(w - 1 + kx) + offv[2 * k + 1];
    const float y0f = floorf(py), x0f = floorf(pxx);
    const float ly = py - y0f, lx = pxx - x0f;
    const int y0 = (int)y0f, x0 = (int)x0f;
    const int y1 = y0 + 1, x1 = x0 + 1;
    float w00 = (1.f - ly) * (1.f - lx), w01 = (1.f - ly) * lx;
    float w10 = ly * (1.f - lx), w11 = ly * lx;
    if (y0 < 0 || y0 >= HH) { w00 = 0.f; w01 = 0.f; }
    if (y1 < 0 || y1 >= HH) { w10 = 0.f; w11 = 0.f; }
    if (x0 < 0 || x0 >= WW) { w00 = 0.f; w10 = 0.f; }
    if (x1 < 0 || x1 >= WW) { w01 = 0.f; w11 = 0.f; }
    const int cy0 = min(max(y0, 0), HH - 1), cy1 = min(max(y1, 0), HH - 1);
    const int cx0 = min(max(x0, 0), WW - 1), cx1 = min(max(x1, 0), WW - 1);

    bf16x8 v00 = *(const bf16x8*)(xb + ((cy0 * WW + cx0) << 6) + c0);
    bf16x8 v01 = *(const bf16x8*)(xb + ((cy0 * WW + cx1) << 6) + c0);
    bf16x8 v10 = *(const bf16x8*)(xb + ((cy1 * WW + cx0) << 6) + c0);
    bf16x8 v11 = *(const bf16x8*)(xb + ((cy1 * WW + cx1) << 6) + c0);

    bf16x8 bs;
#pragma unroll
    for (int j = 0; j < 8; j++) {
      float s = bf2f(v00[j]) * w00 + bf2f(v01[j]) * w01 +
                bf2f(v10[j]) * w10 + bf2f(v11[j]) * w11;
      bs[j] = f2bf(s);
    }

    // weight frags from LDS (contiguous 16B/lane -> ds_read_b128)
    bf16x8 wf0 = *(const bf16x8*)&wlds[buf][((cf * 4 + 0) << 9) + l * 8];
    bf16x8 wf1 = *(const bf16x8*)&wlds[buf][((cf * 4 + 1) << 9) + l * 8];
    bf16x8 wf2 = *(const bf16x8*)&wlds[buf][((cf * 4 + 2) << 9) + l * 8];
    bf16x8 wf3 = *(const bf16x8*)&wlds[buf][((cf * 4 + 3) << 9) + l * 8];

    acc[0] = __builtin_amdgcn_mfma_f32_16x16x32_bf16(wf0, bs, acc[0], 0, 0, 0);
    acc[1] = __builtin_amdgcn_mfma_f32_16x16x32_bf16(wf1, bs, acc[1], 0, 0, 0);
    acc[2] = __builtin_amdgcn_mfma_f32_16x16x32_bf16(wf2, bs, acc[2], 0, 0, 0);
    acc[3] = __builtin_amdgcn_mfma_f32_16x16x32_bf16(wf3, bs, acc[3], 0, 0, 0);

    if (k < 8) __syncthreads();  // stage(k+1) landed; safe to flip buffers
  }

  // 2-way reduce: cf=1 writes, cf=0 adds + outputs
  __syncthreads();
  if (cf == 1) {
#pragma unroll
    for (int ot = 0; ot < 4; ot++)
#pragma unroll
      for (int r = 0; r < 4; r++) red[grp][l][ot * 4 + r] = acc[ot][r];
  }
  __syncthreads();
  if (cf == 0) {
#pragma unroll
    for (int ot = 0; ot < 4; ot++)
#pragma unroll
      for (int r = 0; r < 4; r++)
        acc[ot][r] += red[grp][l][ot * 4 + r] + bias[ot * 16 + quad * 4 + r];
    if (outb) {
#pragma unroll
      for (int ot = 0; ot < 4; ot++) {
        short4 sv;
        sv.x = f2bf(acc[ot][0]); sv.y = f2bf(acc[ot][1]);
        sv.z = f2bf(acc[ot][2]); sv.w = f2bf(acc[ot][3]);
        *(short4*)(outb + (size_t)pix * 64 + ot * 16 + quad * 4) = sv;
      }
    }
    if (outf) {
#pragma unroll
      for (int ot = 0; ot < 4; ot++)
#pragma unroll
        for (int r = 0; r < 4; r++) {
          const int o = ot * 16 + quad * 4 + r;
          outf[(size_t)b * (CC * HW) + (size_t)o * HW + hw] = acc[ot][r];
        }
    }
  }
}

extern "C" void kernel_launch(void* const* d_in, const int* in_sizes, int n_in,
                              void* d_out, int out_size, void* d_ws, size_t ws_size,
                              hipStream_t stream) {
  const float* ref    = (const float*)d_in[0];
  const float* nbr    = (const float*)d_in[1];
  const float* w_off1 = (const float*)d_in[2];
  const float* b_off1 = (const float*)d_in[3];
  const float* w_d1   = (const float*)d_in[4];
  const float* b_d1   = (const float*)d_in[5];
  const float* w_off2 = (const float*)d_in[6];
  const float* b_off2 = (const float*)d_in[7];
  const float* w_d2   = (const float*)d_in[8];
  const float* b_d2   = (const float*)d_in[9];
  const float* w_off3 = (const float*)d_in[10];
  const float* b_off3 = (const float*)d_in[11];
  const float* w_d3   = (const float*)d_in[12];
  const float* b_d3   = (const float*)d_in[13];

  float* out = (float*)d_out;
  char* ws = (char*)d_ws;
  float* off_buf = (float*)(ws);               // 4*16384*20*4 = 5,242,880 B
  short* ref_bf  = (short*)(ws + 5242880);     // 8,388,608 B each
  short* nbr_bf  = (short*)(ws + 13631488);
  short* d1_bf   = (short*)(ws + 22020096);
  short* d2_bf   = (short*)(ws + 30408704);
  short* wtd1    = (short*)(ws + 38797312);    // 73,728 B each
  short* wtd2    = (short*)(ws + 38871040);
  short* wtd3    = (short*)(ws + 38944768);
  short* wtoff1  = (short*)(ws + 39018496);
  short* wtoff2  = (short*)(ws + 39092224);
  short* wtoff3  = (short*)(ws + 39165952);

  cast_nhwc_kernel<<<1024, 256, 0, stream>>>(ref, nbr, ref_bf, nbr_bf);
  prep_weights_all<<<432, 256, 0, stream>>>(
      w_d1, w_off1, wtd1, wtoff1,
      w_d2, w_off2, wtd2, wtoff2,
      w_d3, w_off3, wtd3, wtoff3);

  const int nblk_oc = BB * HW / 16;  // 4096 groups of 16 px
  const int nblk_df = BB * HW / 64;  // 1024 blocks (4 groups x 2 cf waves)

  off_conv_kernel<<<nblk_oc, 256, 0, stream>>>(ref_bf, nbr_bf, wtoff1, b_off1, off_buf);
  deform_cf_kernel<<<nblk_df, 512, 0, stream>>>(nbr_bf, off_buf, wtd1, b_d1, nullptr, d1_bf);
  off_conv_kernel<<<nblk_oc, 256, 0, stream>>>(ref_bf, d1_bf, wtoff2, b_off2, off_buf);
  deform_cf_kernel<<<nblk_df, 512, 0, stream>>>(d1_bf, off_buf, wtd2, b_d2, nullptr, d2_bf);
  off_conv_kernel<<<nblk_oc, 256, 0, stream>>>(ref_bf, d2_bf, wtoff3, b_off3, off_buf);
  deform_cf_kernel<<<nblk_df, 512, 0, stream>>>(d2_bf, off_buf, wtd3, b_d3, out, nullptr);
}

// Round 11
// 240.837 us; speedup vs baseline: 1.0884x; 1.0884x over previous
//
#include <hip/hip_runtime.h>
#include <hip/hip_bf16.h>

#define BB 4
#define CC 64
#define HH 128
#define WW 128
#define HW (HH * WW)
#define OCP 20  // offset channels, padded (18 used)

typedef short bf16x8 __attribute__((ext_vector_type(8)));
typedef float f32x4 __attribute__((ext_vector_type(4)));
typedef float f32x2 __attribute__((ext_vector_type(2)));

static __device__ __forceinline__ short f2bf(float f) {
  __hip_bfloat16 h = __float2bfloat16(f);
  return __builtin_bit_cast(short, h);
}
static __device__ __forceinline__ float bf2f(short s) {
  unsigned int u = ((unsigned int)(unsigned short)s) << 16;
  return __builtin_bit_cast(float, u);
}

// NCHW f32 -> NHWC bf16 for two tensors. Block = 64 px x 64 c tile.
__global__ __launch_bounds__(256) void cast_nhwc_kernel(
    const float* __restrict__ a, const float* __restrict__ b,
    short* __restrict__ oa, short* __restrict__ ob) {
  __shared__ float tile[64][68];
  const int bid = blockIdx.x;        // 1024 blocks
  const int bb = bid >> 8;           // batch
  const int hw0 = (bid & 255) * 64;  // 64-px stripe
  const int t = threadIdx.x;
  for (int s = 0; s < 2; s++) {
    const float* src = s ? b : a;
    short* dst = s ? ob : oa;
    if (s) __syncthreads();
    {
      const int lp = t & 15;  // 16 lanes x float4 = 64 px
      for (int c = (t >> 4); c < 64; c += 16) {
        float4 v = *(const float4*)&src[((size_t)(bb * 64 + c)) * HW + hw0 + lp * 4];
        *(float4*)&tile[c][lp * 4] = v;
      }
    }
    __syncthreads();
    {
      const int px = t >> 2;
      const int seg = t & 3;
      bf16x8 s0, s1;
#pragma unroll
      for (int i = 0; i < 8; i++) s0[i] = f2bf(tile[seg * 16 + i][px]);
#pragma unroll
      for (int i = 0; i < 8; i++) s1[i] = f2bf(tile[seg * 16 + 8 + i][px]);
      short* dp = dst + ((size_t)(bid * 64 + px)) * 64 + seg * 16;
      *(bf16x8*)dp = s0;
      *(bf16x8*)(dp + 8) = s1;
    }
  }
}

// Weight prep, all 3 stages in one launch (stage = blockIdx.x/144).
// deform wd (64,64,3,3) -> A-frags [f = k*8+cf*4+ot][lane][8]:
//   o = ot*16+(l&15), c = cf*32+(l>>4)*8+j
// offset wo (18,128,3,3) -> A-frags [f = (k*4+cs)*2+ot][lane][8]:
//   o = ot*16+(l&15) (zero if o>=18), c = cs*32+(l>>4)*8+j
__global__ __launch_bounds__(256) void prep_weights_all(
    const float* __restrict__ wd1, const float* __restrict__ wo1,
    short* __restrict__ wtd1, short* __restrict__ wtoff1,
    const float* __restrict__ wd2, const float* __restrict__ wo2,
    short* __restrict__ wtd2, short* __restrict__ wtoff2,
    const float* __restrict__ wd3, const float* __restrict__ wo3,
    short* __restrict__ wtd3, short* __restrict__ wtoff3) {
  const int s = blockIdx.x / 144;
  const float* wd = (s == 0) ? wd1 : (s == 1) ? wd2 : wd3;
  const float* wo = (s == 0) ? wo1 : (s == 1) ? wo2 : wo3;
  short* wtd = (s == 0) ? wtd1 : (s == 1) ? wtd2 : wtd3;
  short* wtoff = (s == 0) ? wtoff1 : (s == 1) ? wtoff2 : wtoff3;
  const int i = (blockIdx.x % 144) * 256 + threadIdx.x;  // 0..36863
  const int j = i & 7, l = (i >> 3) & 63, f = i >> 9;
  {
    int ot = f & 3, cf = (f >> 2) & 1, k = f >> 3;
    int o = ot * 16 + (l & 15), c = cf * 32 + (l >> 4) * 8 + j;
    wtd[i] = f2bf(wd[(o * 64 + c) * 9 + k]);
  }
  {
    int ot = f & 1, ks = f >> 1;
    int cs = ks & 3, k = ks >> 2;
    int o = ot * 16 + (l & 15), c = cs * 32 + (l >> 4) * 8 + j;
    wtoff[i] = (o < 18) ? f2bf(wo[(o * 128 + c) * 9 + k]) : (short)0;
  }
}

// ---------- MFMA offset conv, split-K(cs) across 4 waves ----------
// Block = 256 thr = 4 waves, ONE 16-px group. Wave cs handles 32 input
// channels (cs<2: ref, else x2). LDS tree-reduce partial accumulators.
__global__ __launch_bounds__(256, 8) void off_conv_kernel(
    const short* __restrict__ ref, const short* __restrict__ x2,
    const short* __restrict__ wtoff, const float* __restrict__ bias,
    float* __restrict__ out) {
  __shared__ float red[2][64][9];
  int bid = blockIdx.x;
  bid = (bid & 7) * (gridDim.x >> 3) + (bid >> 3);  // XCD swizzle (4096%8==0)
  const int tid = threadIdx.x;
  const int l = tid & 63;
  const int cs = __builtin_amdgcn_readfirstlane(tid >> 6);  // wave = c-slice
  const int col = l & 15, quad = l >> 4;
  const int pix = bid * 16 + col;
  const int b = pix >> 14, hw = pix & (HW - 1);
  const int h = hw >> 7, w = hw & (WW - 1);

  f32x4 acc0 = {0.f, 0.f, 0.f, 0.f}, acc1 = {0.f, 0.f, 0.f, 0.f};
  const int c0 = (cs & 1) * 32 + quad * 8;
  const short* src = (cs < 2) ? ref : x2;
  const bf16x8* wp = (const bf16x8*)wtoff + l;

#pragma unroll
  for (int k = 0; k < 9; k++) {
    const int ky = k / 3, kx = k - ky * 3;
    const int hh = h + ky - 1, ww2 = w + kx - 1;
    const bool valid = (hh >= 0) & (hh < HH) & (ww2 >= 0) & (ww2 < WW);
    const int chh = min(max(hh, 0), HH - 1), cww = min(max(ww2, 0), WW - 1);
    bf16x8 v = *(const bf16x8*)(src + ((b * HW + chh * WW + cww) << 6) + c0);
    if (!valid) v = (bf16x8)(short)0;
    acc0 = __builtin_amdgcn_mfma_f32_16x16x32_bf16(
        wp[((k * 4 + cs) * 2 + 0) * 64], v, acc0, 0, 0, 0);
    acc1 = __builtin_amdgcn_mfma_f32_16x16x32_bf16(
        wp[((k * 4 + cs) * 2 + 1) * 64], v, acc1, 0, 0, 0);
  }

  // tree reduce: 4 -> 2 -> 1
  if (cs >= 2) {
#pragma unroll
    for (int r = 0; r < 4; r++) {
      red[cs - 2][l][r] = acc0[r];
      red[cs - 2][l][4 + r] = acc1[r];
    }
  }
  __syncthreads();
  if (cs < 2) {
#pragma unroll
    for (int r = 0; r < 4; r++) {
      acc0[r] += red[cs][l][r];
      acc1[r] += red[cs][l][4 + r];
    }
  }
  __syncthreads();
  if (cs == 1) {
#pragma unroll
    for (int r = 0; r < 4; r++) {
      red[0][l][r] = acc0[r];
      red[0][l][4 + r] = acc1[r];
    }
  }
  __syncthreads();
  if (cs == 0) {
    float* po = out + (size_t)pix * OCP;
#pragma unroll
    for (int r = 0; r < 4; r++)
      po[quad * 4 + r] = acc0[r] + red[0][l][r] + bias[quad * 4 + r];
    if (quad == 0) {
      po[16] = acc1[0] + red[0][l][4] + bias[16];
      po[17] = acc1[1] + red[0][l][5] + bias[17];
    }
  }
}

// ---------- MFMA deformable conv: post-MFMA bilinear (linearity) ----------
// Block = 512 thr = 4 px-groups x 2 cf-waves (r9 layout). Per tap: 4 RAW
// corner gathers go STRAIGHT into MFMA (no blend, no repack); the bilinear
// weight (per-pixel = per-C-column = per-lane scalar) is applied after:
//   acc_ot += w_corner * mfma(W_ot, v_corner, 0)
// Tap k+1's 8 loads are issued before COMP(k), pinned by sched_barrier.
#define MF(a, b, c) __builtin_amdgcn_mfma_f32_16x16x32_bf16(a, b, c, 0, 0, 0)

#define PM_STAGE(k, S)                                                      \
  {                                                                         \
    const int ky = (k) / 3, kx = (k) - ky * 3;                              \
    const float py = (float)(h - 1 + ky) + offv[2 * (k)];                   \
    const float pxx = (float)(w - 1 + kx) + offv[2 * (k) + 1];              \
    const float y0f = floorf(py), x0f = floorf(pxx);                        \
    const float ly = py - y0f, lx = pxx - x0f;                              \
    const int y0 = (int)y0f, x0 = (int)x0f;                                 \
    const int y1 = y0 + 1, x1 = x0 + 1;                                     \
    float w00 = (1.f - ly) * (1.f - lx), w01 = (1.f - ly) * lx;             \
    float w10 = ly * (1.f - lx), w11 = ly * lx;                             \
    if (y0 < 0 || y0 >= HH) { w00 = 0.f; w01 = 0.f; }                       \
    if (y1 < 0 || y1 >= HH) { w10 = 0.f; w11 = 0.f; }                       \
    if (x0 < 0 || x0 >= WW) { w00 = 0.f; w10 = 0.f; }                       \
    if (x1 < 0 || x1 >= WW) { w01 = 0.f; w11 = 0.f; }                       \
    const int cy0 = min(max(y0, 0), HH - 1), cy1 = min(max(y1, 0), HH - 1); \
    const int cx0 = min(max(x0, 0), WW - 1), cx1 = min(max(x1, 0), WW - 1); \
    cb##S##0 = *(const bf16x8*)(xb + ((cy0 * WW + cx0) << 6) + c0);         \
    cb##S##1 = *(const bf16x8*)(xb + ((cy0 * WW + cx1) << 6) + c0);         \
    cb##S##2 = *(const bf16x8*)(xb + ((cy1 * WW + cx0) << 6) + c0);         \
    cb##S##3 = *(const bf16x8*)(xb + ((cy1 * WW + cx1) << 6) + c0);         \
    wf##S##0 = wp[((k) * 8 + cf * 4 + 0) * 64];                             \
    wf##S##1 = wp[((k) * 8 + cf * 4 + 1) * 64];                             \
    wf##S##2 = wp[((k) * 8 + cf * 4 + 2) * 64];                             \
    wf##S##3 = wp[((k) * 8 + cf * 4 + 3) * 64];                             \
    sw##S##0 = w00; sw##S##1 = w01; sw##S##2 = w10; sw##S##3 = w11;         \
  }

#define PM_COMP(S)                                                          \
  {                                                                         \
    f32x4 t0, t1, t2, t3, u0, u1, u2, u3;                                   \
    t0 = MF(wf##S##0, cb##S##0, zz); t1 = MF(wf##S##1, cb##S##0, zz);       \
    t2 = MF(wf##S##2, cb##S##0, zz); t3 = MF(wf##S##3, cb##S##0, zz);       \
    u0 = MF(wf##S##0, cb##S##1, zz); u1 = MF(wf##S##1, cb##S##1, zz);       \
    u2 = MF(wf##S##2, cb##S##1, zz); u3 = MF(wf##S##3, cb##S##1, zz);       \
    acc0 += t0 * sw##S##0; acc1 += t1 * sw##S##0;                           \
    acc2 += t2 * sw##S##0; acc3 += t3 * sw##S##0;                           \
    t0 = MF(wf##S##0, cb##S##2, zz); t1 = MF(wf##S##1, cb##S##2, zz);       \
    t2 = MF(wf##S##2, cb##S##2, zz); t3 = MF(wf##S##3, cb##S##2, zz);       \
    acc0 += u0 * sw##S##1; acc1 += u1 * sw##S##1;                           \
    acc2 += u2 * sw##S##1; acc3 += u3 * sw##S##1;                           \
    u0 = MF(wf##S##0, cb##S##3, zz); u1 = MF(wf##S##1, cb##S##3, zz);       \
    u2 = MF(wf##S##2, cb##S##3, zz); u3 = MF(wf##S##3, cb##S##3, zz);       \
    acc0 += t0 * sw##S##2; acc1 += t1 * sw##S##2;                           \
    acc2 += t2 * sw##S##2; acc3 += t3 * sw##S##2;                           \
    acc0 += u0 * sw##S##3; acc1 += u1 * sw##S##3;                           \
    acc2 += u2 * sw##S##3; acc3 += u3 * sw##S##3;                           \
  }

__global__ __launch_bounds__(512, 3) void deform_pm_kernel(
    const short* __restrict__ x, const float* __restrict__ off,
    const short* __restrict__ wtd, const float* __restrict__ bias,
    float* __restrict__ outf, short* __restrict__ outb) {
  __shared__ float red[4][64][17];
  int bid = blockIdx.x;
  bid = (bid & 7) * (gridDim.x >> 3) + (bid >> 3);  // 1024 % 8 == 0
  const int tid = threadIdx.x;
  const int l = tid & 63;
  const int wv = __builtin_amdgcn_readfirstlane(tid >> 6);  // 0..7
  const int grp = wv >> 1;  // px group 0..3
  const int cf = wv & 1;    // channel half
  const int col = l & 15, quad = l >> 4;
  const int pix = bid * 64 + grp * 16 + col;
  const int b = pix >> 14, hw = pix & (HW - 1);
  const int h = hw >> 7, w = hw & (WW - 1);

  const short* xb = x + (size_t)b * (HW * 64);
  const float* offp = off + (size_t)pix * OCP;

  // all 18 offset values in 5 vector loads
  f32x4 ov0 = *(const f32x4*)(offp);
  f32x4 ov1 = *(const f32x4*)(offp + 4);
  f32x4 ov2 = *(const f32x4*)(offp + 8);
  f32x4 ov3 = *(const f32x4*)(offp + 12);
  f32x2 ov4 = *(const f32x2*)(offp + 16);
  float offv[18];
#pragma unroll
  for (int i = 0; i < 4; i++) offv[i] = ov0[i];
#pragma unroll
  for (int i = 0; i < 4; i++) offv[4 + i] = ov1[i];
#pragma unroll
  for (int i = 0; i < 4; i++) offv[8 + i] = ov2[i];
#pragma unroll
  for (int i = 0; i < 4; i++) offv[12 + i] = ov3[i];
  offv[16] = ov4[0];
  offv[17] = ov4[1];

  const f32x4 zz = {0.f, 0.f, 0.f, 0.f};
  f32x4 acc0 = zz, acc1 = zz, acc2 = zz, acc3 = zz;

  const int c0 = cf * 32 + quad * 8;
  const bf16x8* wp = (const bf16x8*)wtd + l;

  bf16x8 cb00, cb01, cb02, cb03, cb10, cb11, cb12, cb13;
  bf16x8 wf00, wf01, wf02, wf03, wf10, wf11, wf12, wf13;
  float sw00, sw01, sw02, sw03, sw10, sw11, sw12, sw13;

  PM_STAGE(0, 0)
#pragma unroll
  for (int k = 0; k < 9; k++) {
    if (k < 8) {
      if ((k & 1) == 0) { PM_STAGE(k + 1, 1) }
      else              { PM_STAGE(k + 1, 0) }
    }
    __builtin_amdgcn_sched_barrier(0);
    if ((k & 1) == 0) { PM_COMP(0) }
    else              { PM_COMP(1) }
  }

  // 2-way reduce: cf=1 writes, cf=0 adds + outputs
  if (cf == 1) {
#pragma unroll
    for (int r = 0; r < 4; r++) {
      red[grp][l][0 + r] = acc0[r];
      red[grp][l][4 + r] = acc1[r];
      red[grp][l][8 + r] = acc2[r];
      red[grp][l][12 + r] = acc3[r];
    }
  }
  __syncthreads();
  if (cf == 0) {
    f32x4 fa[4] = {acc0, acc1, acc2, acc3};
#pragma unroll
    for (int ot = 0; ot < 4; ot++)
#pragma unroll
      for (int r = 0; r < 4; r++)
        fa[ot][r] += red[grp][l][ot * 4 + r] + bias[ot * 16 + quad * 4 + r];
    if (outb) {
#pragma unroll
      for (int ot = 0; ot < 4; ot++) {
        short4 sv;
        sv.x = f2bf(fa[ot][0]); sv.y = f2bf(fa[ot][1]);
        sv.z = f2bf(fa[ot][2]); sv.w = f2bf(fa[ot][3]);
        *(short4*)(outb + (size_t)pix * 64 + ot * 16 + quad * 4) = sv;
      }
    }
    if (outf) {
#pragma unroll
      for (int ot = 0; ot < 4; ot++)
#pragma unroll
        for (int r = 0; r < 4; r++) {
          const int o = ot * 16 + quad * 4 + r;
          outf[(size_t)b * (CC * HW) + (size_t)o * HW + hw] = fa[ot][r];
        }
    }
  }
}

extern "C" void kernel_launch(void* const* d_in, const int* in_sizes, int n_in,
                              void* d_out, int out_size, void* d_ws, size_t ws_size,
                              hipStream_t stream) {
  const float* ref    = (const float*)d_in[0];
  const float* nbr    = (const float*)d_in[1];
  const float* w_off1 = (const float*)d_in[2];
  const float* b_off1 = (const float*)d_in[3];
  const float* w_d1   = (const float*)d_in[4];
  const float* b_d1   = (const float*)d_in[5];
  const float* w_off2 = (const float*)d_in[6];
  const float* b_off2 = (const float*)d_in[7];
  const float* w_d2   = (const float*)d_in[8];
  const float* b_d2   = (const float*)d_in[9];
  const float* w_off3 = (const float*)d_in[10];
  const float* b_off3 = (const float*)d_in[11];
  const float* w_d3   = (const float*)d_in[12];
  const float* b_d3   = (const float*)d_in[13];

  float* out = (float*)d_out;
  char* ws = (char*)d_ws;
  float* off_buf = (float*)(ws);               // 4*16384*20*4 = 5,242,880 B
  short* ref_bf  = (short*)(ws + 5242880);     // 8,388,608 B each
  short* nbr_bf  = (short*)(ws + 13631488);
  short* d1_bf   = (short*)(ws + 22020096);
  short* d2_bf   = (short*)(ws + 30408704);
  short* wtd1    = (short*)(ws + 38797312);    // 73,728 B each
  short* wtd2    = (short*)(ws + 38871040);
  short* wtd3    = (short*)(ws + 38944768);
  short* wtoff1  = (short*)(ws + 39018496);
  short* wtoff2  = (short*)(ws + 39092224);
  short* wtoff3  = (short*)(ws + 39165952);

  cast_nhwc_kernel<<<1024, 256, 0, stream>>>(ref, nbr, ref_bf, nbr_bf);
  prep_weights_all<<<432, 256, 0, stream>>>(
      w_d1, w_off1, wtd1, wtoff1,
      w_d2, w_off2, wtd2, wtoff2,
      w_d3, w_off3, wtd3, wtoff3);

  const int nblk_oc = BB * HW / 16;  // 4096 groups of 16 px
  const int nblk_df = BB * HW / 64;  // 1024 blocks (4 groups x 2 cf waves)

  off_conv_kernel<<<nblk_oc, 256, 0, stream>>>(ref_bf, nbr_bf, wtoff1, b_off1, off_buf);
  deform_pm_kernel<<<nblk_df, 512, 0, stream>>>(nbr_bf, off_buf, wtd1, b_d1, nullptr, d1_bf);
  off_conv_kernel<<<nblk_oc, 256, 0, stream>>>(ref_bf, d1_bf, wtoff2, b_off2, off_buf);
  deform_pm_kernel<<<nblk_df, 512, 0, stream>>>(d1_bf, off_buf, wtd2, b_d2, nullptr, d2_bf);
  off_conv_kernel<<<nblk_oc, 256, 0, stream>>>(ref_bf, d2_bf, wtoff3, b_off3, off_buf);
  deform_pm_kernel<<<nblk_df, 512, 0, stream>>>(d2_bf, off_buf, wtd3, b_d3, out, nullptr);
}

// Round 12
// 166.498 us; speedup vs baseline: 1.5744x; 1.4465x over previous
//
#include <hip/hip_runtime.h>
#include <hip/hip_bf16.h>

#define BB 4
#define CC 64
#define HH 128
#define WW 128
#define HW (HH * WW)
#define OCP 20  // offset channels, padded (18 used)

typedef short bf16x8 __attribute__((ext_vector_type(8)));
typedef float f32x4 __attribute__((ext_vector_type(4)));
typedef float f32x2 __attribute__((ext_vector_type(2)));

static __device__ __forceinline__ short f2bf(float f) {
  __hip_bfloat16 h = __float2bfloat16(f);
  return __builtin_bit_cast(short, h);
}
static __device__ __forceinline__ float bf2f(short s) {
  unsigned int u = ((unsigned int)(unsigned short)s) << 16;
  return __builtin_bit_cast(float, u);
}

// async 16B/lane global -> LDS (wave-uniform LDS base + lane*16)
static __device__ __forceinline__ void stage1k(const short* g, short* lds) {
  __builtin_amdgcn_global_load_lds(
      (const __attribute__((address_space(1))) unsigned int*)g,
      (__attribute__((address_space(3))) unsigned int*)lds, 16, 0, 0);
}

// NCHW f32 -> NHWC bf16 for two tensors. Block = 64 px x 64 c tile.
__global__ __launch_bounds__(256) void cast_nhwc_kernel(
    const float* __restrict__ a, const float* __restrict__ b,
    short* __restrict__ oa, short* __restrict__ ob) {
  __shared__ float tile[64][68];
  const int bid = blockIdx.x;        // 1024 blocks
  const int bb = bid >> 8;           // batch
  const int hw0 = (bid & 255) * 64;  // 64-px stripe
  const int t = threadIdx.x;
  for (int s = 0; s < 2; s++) {
    const float* src = s ? b : a;
    short* dst = s ? ob : oa;
    if (s) __syncthreads();
    {
      const int lp = t & 15;  // 16 lanes x float4 = 64 px
      for (int c = (t >> 4); c < 64; c += 16) {
        float4 v = *(const float4*)&src[((size_t)(bb * 64 + c)) * HW + hw0 + lp * 4];
        *(float4*)&tile[c][lp * 4] = v;
      }
    }
    __syncthreads();
    {
      const int px = t >> 2;
      const int seg = t & 3;
      bf16x8 s0, s1;
#pragma unroll
      for (int i = 0; i < 8; i++) s0[i] = f2bf(tile[seg * 16 + i][px]);
#pragma unroll
      for (int i = 0; i < 8; i++) s1[i] = f2bf(tile[seg * 16 + 8 + i][px]);
      short* dp = dst + ((size_t)(bid * 64 + px)) * 64 + seg * 16;
      *(bf16x8*)dp = s0;
      *(bf16x8*)(dp + 8) = s1;
    }
  }
}

// Weight prep, all 3 stages in one launch (stage = blockIdx.x/144).
__global__ __launch_bounds__(256) void prep_weights_all(
    const float* __restrict__ wd1, const float* __restrict__ wo1,
    short* __restrict__ wtd1, short* __restrict__ wtoff1,
    const float* __restrict__ wd2, const float* __restrict__ wo2,
    short* __restrict__ wtd2, short* __restrict__ wtoff2,
    const float* __restrict__ wd3, const float* __restrict__ wo3,
    short* __restrict__ wtd3, short* __restrict__ wtoff3) {
  const int s = blockIdx.x / 144;
  const float* wd = (s == 0) ? wd1 : (s == 1) ? wd2 : wd3;
  const float* wo = (s == 0) ? wo1 : (s == 1) ? wo2 : wo3;
  short* wtd = (s == 0) ? wtd1 : (s == 1) ? wtd2 : wtd3;
  short* wtoff = (s == 0) ? wtoff1 : (s == 1) ? wtoff2 : wtoff3;
  const int i = (blockIdx.x % 144) * 256 + threadIdx.x;  // 0..36863
  const int j = i & 7, l = (i >> 3) & 63, f = i >> 9;
  {
    int ot = f & 3, cf = (f >> 2) & 1, k = f >> 3;
    int o = ot * 16 + (l & 15), c = cf * 32 + (l >> 4) * 8 + j;
    wtd[i] = f2bf(wd[(o * 64 + c) * 9 + k]);
  }
  {
    int ot = f & 1, ks = f >> 1;
    int cs = ks & 3, k = ks >> 2;
    int o = ot * 16 + (l & 15), c = cs * 32 + (l >> 4) * 8 + j;
    wtoff[i] = (o < 18) ? f2bf(wo[(o * 128 + c) * 9 + k]) : (short)0;
  }
}

// ---------- MFMA offset conv, split-K(cs) across 4 waves (r8) ----------
__global__ __launch_bounds__(256, 8) void off_conv_kernel(
    const short* __restrict__ ref, const short* __restrict__ x2,
    const short* __restrict__ wtoff, const float* __restrict__ bias,
    float* __restrict__ out) {
  __shared__ float red[2][64][9];
  int bid = blockIdx.x;
  bid = (bid & 7) * (gridDim.x >> 3) + (bid >> 3);
  const int tid = threadIdx.x;
  const int l = tid & 63;
  const int cs = __builtin_amdgcn_readfirstlane(tid >> 6);
  const int col = l & 15, quad = l >> 4;
  const int pix = bid * 16 + col;
  const int b = pix >> 14, hw = pix & (HW - 1);
  const int h = hw >> 7, w = hw & (WW - 1);

  f32x4 acc0 = {0.f, 0.f, 0.f, 0.f}, acc1 = {0.f, 0.f, 0.f, 0.f};
  const int c0 = (cs & 1) * 32 + quad * 8;
  const short* src = (cs < 2) ? ref : x2;
  const bf16x8* wp = (const bf16x8*)wtoff + l;

#pragma unroll
  for (int k = 0; k < 9; k++) {
    const int ky = k / 3, kx = k - ky * 3;
    const int hh = h + ky - 1, ww2 = w + kx - 1;
    const bool valid = (hh >= 0) & (hh < HH) & (ww2 >= 0) & (ww2 < WW);
    const int chh = min(max(hh, 0), HH - 1), cww = min(max(ww2, 0), WW - 1);
    bf16x8 v = *(const bf16x8*)(src + ((b * HW + chh * WW + cww) << 6) + c0);
    if (!valid) v = (bf16x8)(short)0;
    acc0 = __builtin_amdgcn_mfma_f32_16x16x32_bf16(
        wp[((k * 4 + cs) * 2 + 0) * 64], v, acc0, 0, 0, 0);
    acc1 = __builtin_amdgcn_mfma_f32_16x16x32_bf16(
        wp[((k * 4 + cs) * 2 + 1) * 64], v, acc1, 0, 0, 0);
  }

  if (cs >= 2) {
#pragma unroll
    for (int r = 0; r < 4; r++) {
      red[cs - 2][l][r] = acc0[r];
      red[cs - 2][l][4 + r] = acc1[r];
    }
  }
  __syncthreads();
  if (cs < 2) {
#pragma unroll
    for (int r = 0; r < 4; r++) {
      acc0[r] += red[cs][l][r];
      acc1[r] += red[cs][l][4 + r];
    }
  }
  __syncthreads();
  if (cs == 1) {
#pragma unroll
    for (int r = 0; r < 4; r++) {
      red[0][l][r] = acc0[r];
      red[0][l][4 + r] = acc1[r];
    }
  }
  __syncthreads();
  if (cs == 0) {
    float* po = out + (size_t)pix * OCP;
#pragma unroll
    for (int r = 0; r < 4; r++)
      po[quad * 4 + r] = acc0[r] + red[0][l][r] + bias[quad * 4 + r];
    if (quad == 0) {
      po[16] = acc1[0] + red[0][l][4] + bias[16];
      po[17] = acc1[1] + red[0][l][5] + bias[17];
    }
  }
}

// ---------- LDS-tiled MFMA deformable conv ----------
// Block = 512 thr = 8 waves; output tile = 8 rows x 16 cols px.
// Stage a 16x24 px NHWC halo tile (49KB, chunk-swizzled slot=(chunk+tc)&7)
// via global_load_lds; all corner gathers become ds_read_b128. Wave-uniform
// fallback to global loads when any corner falls outside the tile.
#define TH 16
#define TWP 24
__global__ __launch_bounds__(512, 4) void deform_tile_kernel(
    const short* __restrict__ x, const float* __restrict__ off,
    const short* __restrict__ wtd, const float* __restrict__ bias,
    float* __restrict__ outf, short* __restrict__ outb) {
  __shared__ short tile[TH * TWP * 64];  // 49152 B
  int bid = blockIdx.x;
  bid = (bid & 7) * (gridDim.x >> 3) + (bid >> 3);  // 512 % 8 == 0
  const int tid = threadIdx.x;
  const int l = tid & 63;
  const int wv = __builtin_amdgcn_readfirstlane(tid >> 6);  // 0..7
  const int col = l & 15, quad = l >> 4;
  const int b = bid >> 7;
  const int rem = bid & 127;
  const int h0 = (rem >> 3) * 8;   // 16 row-tiles
  const int w0 = (rem & 7) * 16;   // 8 col-tiles
  const int oy = h0 - 4, ox = w0 - 4;
  const int h = h0 + wv, w = w0 + col;
  const int pix = ((b << 7) + h) * WW + w;  // b*HW + h*128 + w

  const short* xb = x + (size_t)b * (HW * 64);

  // ---- stage 16x24-px halo tile, chunk-swizzled source ----
  {
    const int tc = ((l >> 3) & 7);  // pixel-in-segment 0..7 (l/8)
    const int m = l & 7;            // dest chunk slot
#pragma unroll
    for (int i = 0; i < 6; i++) {
      const int idx = wv + i * 8;        // 0..47
      const int r = idx / 3, seg = idx % 3;
      const int iy = min(max(oy + r, 0), HH - 1);
      const int tcol = seg * 8 + tc;
      const int ix = min(max(ox + tcol, 0), WW - 1);
      const int sc = (m - tcol) & 7;     // source channel chunk
      stage1k(xb + (((iy << 7) + ix) << 6) + sc * 8,
              &tile[((r * TWP + seg * 8) << 6)]);
    }
  }

  // offsets (independent of staging)
  const float* offp = off + (size_t)pix * OCP;
  f32x4 ov0 = *(const f32x4*)(offp);
  f32x4 ov1 = *(const f32x4*)(offp + 4);
  f32x4 ov2 = *(const f32x4*)(offp + 8);
  f32x4 ov3 = *(const f32x4*)(offp + 12);
  f32x2 ov4 = *(const f32x2*)(offp + 16);
  float offv[18];
#pragma unroll
  for (int i = 0; i < 4; i++) offv[i] = ov0[i];
#pragma unroll
  for (int i = 0; i < 4; i++) offv[4 + i] = ov1[i];
#pragma unroll
  for (int i = 0; i < 4; i++) offv[8 + i] = ov2[i];
#pragma unroll
  for (int i = 0; i < 4; i++) offv[12 + i] = ov3[i];
  offv[16] = ov4[0];
  offv[17] = ov4[1];

  f32x4 acc[4];
#pragma unroll
  for (int ot = 0; ot < 4; ot++)
#pragma unroll
    for (int r = 0; r < 4; r++) acc[ot][r] = 0.f;

  const int c0g = quad * 8;  // global-path channel base (cf 0 chunk)
  const bf16x8* wp = (const bf16x8*)wtd + l;

  __syncthreads();  // tile staged (drains vmcnt)

#pragma unroll
  for (int k = 0; k < 9; k++) {
    const int ky = k / 3, kx = k - ky * 3;
    const float py = (float)(h - 1 + ky) + offv[2 * k];
    const float pxx = (float)(w - 1 + kx) + offv[2 * k + 1];
    const float y0f = floorf(py), x0f = floorf(pxx);
    const float ly = py - y0f, lx = pxx - x0f;
    const int y0 = (int)y0f, x0 = (int)x0f;
    const int y1 = y0 + 1, x1 = x0 + 1;
    float w00 = (1.f - ly) * (1.f - lx), w01 = (1.f - ly) * lx;
    float w10 = ly * (1.f - lx), w11 = ly * lx;
    if (y0 < 0 || y0 >= HH) { w00 = 0.f; w01 = 0.f; }
    if (y1 < 0 || y1 >= HH) { w10 = 0.f; w11 = 0.f; }
    if (x0 < 0 || x0 >= WW) { w00 = 0.f; w10 = 0.f; }
    if (x1 < 0 || x1 >= WW) { w01 = 0.f; w11 = 0.f; }
    const int cy0 = min(max(y0, 0), HH - 1), cy1 = min(max(y1, 0), HH - 1);
    const int cx0 = min(max(x0, 0), WW - 1), cx1 = min(max(x1, 0), WW - 1);

    const int ty0 = cy0 - oy, ty1 = cy1 - oy;
    const int tx0 = cx0 - ox, tx1 = cx1 - ox;
    const bool intile = (ty0 >= 0) & (ty1 < TH) & (tx0 >= 0) & (tx1 < TWP);

    bf16x8 v00a, v00b, v01a, v01b, v10a, v10b, v11a, v11b;
    if (__builtin_amdgcn_ballot_w64(intile) == ~0ull) {
      // ---- LDS fast path (swizzled ds_read_b128) ----
      const int p00 = ((ty0 * TWP + tx0) << 6);
      const int p01 = ((ty0 * TWP + tx1) << 6);
      const int p10 = ((ty1 * TWP + tx0) << 6);
      const int p11 = ((ty1 * TWP + tx1) << 6);
      v00a = *(const bf16x8*)&tile[p00 + (((quad + tx0) & 7) << 3)];
      v00b = *(const bf16x8*)&tile[p00 + (((quad + 4 + tx0) & 7) << 3)];
      v01a = *(const bf16x8*)&tile[p01 + (((quad + tx1) & 7) << 3)];
      v01b = *(const bf16x8*)&tile[p01 + (((quad + 4 + tx1) & 7) << 3)];
      v10a = *(const bf16x8*)&tile[p10 + (((quad + tx0) & 7) << 3)];
      v10b = *(const bf16x8*)&tile[p10 + (((quad + 4 + tx0) & 7) << 3)];
      v11a = *(const bf16x8*)&tile[p11 + (((quad + tx1) & 7) << 3)];
      v11b = *(const bf16x8*)&tile[p11 + (((quad + 4 + tx1) & 7) << 3)];
    } else {
      // ---- global fallback (rare: |offset| beyond halo) ----
      const int p00 = ((cy0 * WW + cx0) << 6) + c0g;
      const int p01 = ((cy0 * WW + cx1) << 6) + c0g;
      const int p10 = ((cy1 * WW + cx0) << 6) + c0g;
      const int p11 = ((cy1 * WW + cx1) << 6) + c0g;
      v00a = *(const bf16x8*)(xb + p00);
      v00b = *(const bf16x8*)(xb + p00 + 32);
      v01a = *(const bf16x8*)(xb + p01);
      v01b = *(const bf16x8*)(xb + p01 + 32);
      v10a = *(const bf16x8*)(xb + p10);
      v10b = *(const bf16x8*)(xb + p10 + 32);
      v11a = *(const bf16x8*)(xb + p11);
      v11b = *(const bf16x8*)(xb + p11 + 32);
    }

    bf16x8 bs0, bs1;
#pragma unroll
    for (int j = 0; j < 8; j++) {
      float sa = bf2f(v00a[j]) * w00 + bf2f(v01a[j]) * w01 +
                 bf2f(v10a[j]) * w10 + bf2f(v11a[j]) * w11;
      bs0[j] = f2bf(sa);
      float sb = bf2f(v00b[j]) * w00 + bf2f(v01b[j]) * w01 +
                 bf2f(v10b[j]) * w10 + bf2f(v11b[j]) * w11;
      bs1[j] = f2bf(sb);
    }

    acc[0] = __builtin_amdgcn_mfma_f32_16x16x32_bf16(wp[(k * 8 + 0) * 64], bs0, acc[0], 0, 0, 0);
    acc[1] = __builtin_amdgcn_mfma_f32_16x16x32_bf16(wp[(k * 8 + 1) * 64], bs0, acc[1], 0, 0, 0);
    acc[2] = __builtin_amdgcn_mfma_f32_16x16x32_bf16(wp[(k * 8 + 2) * 64], bs0, acc[2], 0, 0, 0);
    acc[3] = __builtin_amdgcn_mfma_f32_16x16x32_bf16(wp[(k * 8 + 3) * 64], bs0, acc[3], 0, 0, 0);
    acc[0] = __builtin_amdgcn_mfma_f32_16x16x32_bf16(wp[(k * 8 + 4) * 64], bs1, acc[0], 0, 0, 0);
    acc[1] = __builtin_amdgcn_mfma_f32_16x16x32_bf16(wp[(k * 8 + 5) * 64], bs1, acc[1], 0, 0, 0);
    acc[2] = __builtin_amdgcn_mfma_f32_16x16x32_bf16(wp[(k * 8 + 6) * 64], bs1, acc[2], 0, 0, 0);
    acc[3] = __builtin_amdgcn_mfma_f32_16x16x32_bf16(wp[(k * 8 + 7) * 64], bs1, acc[3], 0, 0, 0);
  }

#pragma unroll
  for (int ot = 0; ot < 4; ot++)
#pragma unroll
    for (int r = 0; r < 4; r++)
      acc[ot][r] += bias[ot * 16 + quad * 4 + r];

  if (outb) {
#pragma unroll
    for (int ot = 0; ot < 4; ot++) {
      short4 sv;
      sv.x = f2bf(acc[ot][0]); sv.y = f2bf(acc[ot][1]);
      sv.z = f2bf(acc[ot][2]); sv.w = f2bf(acc[ot][3]);
      *(short4*)(outb + (size_t)pix * 64 + ot * 16 + quad * 4) = sv;
    }
  }
  if (outf) {
    const int hw = pix & (HW - 1);
#pragma unroll
    for (int ot = 0; ot < 4; ot++)
#pragma unroll
      for (int r = 0; r < 4; r++) {
        const int o = ot * 16 + quad * 4 + r;
        outf[(size_t)b * (CC * HW) + (size_t)o * HW + hw] = acc[ot][r];
      }
  }
}

extern "C" void kernel_launch(void* const* d_in, const int* in_sizes, int n_in,
                              void* d_out, int out_size, void* d_ws, size_t ws_size,
                              hipStream_t stream) {
  const float* ref    = (const float*)d_in[0];
  const float* nbr    = (const float*)d_in[1];
  const float* w_off1 = (const float*)d_in[2];
  const float* b_off1 = (const float*)d_in[3];
  const float* w_d1   = (const float*)d_in[4];
  const float* b_d1   = (const float*)d_in[5];
  const float* w_off2 = (const float*)d_in[6];
  const float* b_off2 = (const float*)d_in[7];
  const float* w_d2   = (const float*)d_in[8];
  const float* b_d2   = (const float*)d_in[9];
  const float* w_off3 = (const float*)d_in[10];
  const float* b_off3 = (const float*)d_in[11];
  const float* w_d3   = (const float*)d_in[12];
  const float* b_d3   = (const float*)d_in[13];

  float* out = (float*)d_out;
  char* ws = (char*)d_ws;
  float* off_buf = (float*)(ws);               // 5,242,880 B
  short* ref_bf  = (short*)(ws + 5242880);     // 8,388,608 B each
  short* nbr_bf  = (short*)(ws + 13631488);
  short* d1_bf   = (short*)(ws + 22020096);
  short* d2_bf   = (short*)(ws + 30408704);
  short* wtd1    = (short*)(ws + 38797312);    // 73,728 B each
  short* wtd2    = (short*)(ws + 38871040);
  short* wtd3    = (short*)(ws + 38944768);
  short* wtoff1  = (short*)(ws + 39018496);
  short* wtoff2  = (short*)(ws + 39092224);
  short* wtoff3  = (short*)(ws + 39165952);

  cast_nhwc_kernel<<<1024, 256, 0, stream>>>(ref, nbr, ref_bf, nbr_bf);
  prep_weights_all<<<432, 256, 0, stream>>>(
      w_d1, w_off1, wtd1, wtoff1,
      w_d2, w_off2, wtd2, wtoff2,
      w_d3, w_off3, wtd3, wtoff3);

  const int nblk_oc = BB * HW / 16;   // 4096
  const int nblk_df = BB * HW / 128;  // 512 tiles of 8x16 px

  off_conv_kernel<<<nblk_oc, 256, 0, stream>>>(ref_bf, nbr_bf, wtoff1, b_off1, off_buf);
  deform_tile_kernel<<<nblk_df, 512, 0, stream>>>(nbr_bf, off_buf, wtd1, b_d1, nullptr, d1_bf);
  off_conv_kernel<<<nblk_oc, 256, 0, stream>>>(ref_bf, d1_bf, wtoff2, b_off2, off_buf);
  deform_tile_kernel<<<nblk_df, 512, 0, stream>>>(d1_bf, off_buf, wtd2, b_d2, nullptr, d2_bf);
  off_conv_kernel<<<nblk_oc, 256, 0, stream>>>(ref_bf, d2_bf, wtoff3, b_off3, off_buf);
  deform_tile_kernel<<<nblk_df, 512, 0, stream>>>(d2_bf, off_buf, wtd3, b_d3, out, nullptr);
}